// Round 2
// 772.340 us; speedup vs baseline: 1.1552x; 1.1552x over previous
//
#include <hip/hip_runtime.h>
#include <math.h>

#define NB 4
#define NCX 16
#define NC1 16
#define NCA 8
#define NN 1024
#define ND 64
#define NL 64
#define LSTRIDE 1025   // LDS row stride (floats): 1025 % 32 == 1 -> conflict-free

typedef __attribute__((ext_vector_type(8))) short bf16x8;
typedef __attribute__((ext_vector_type(4))) float f32x4;
typedef unsigned short u16;
typedef unsigned int u32;

// RNE float -> bf16 bits
__device__ __forceinline__ u16 f2b(float f) {
    u32 u = __float_as_uint(f);
    return (u16)((u + 0x7FFFu + ((u >> 16) & 1u)) >> 16);
}

// load 8 consecutive floats, convert to a bf16 MFMA fragment
__device__ __forceinline__ bf16x8 cvt8(const float* __restrict__ p) {
    float4 a = *(const float4*)p;
    float4 b = *(const float4*)(p + 4);
    bf16x8 r;
    r[0] = (short)f2b(a.x); r[1] = (short)f2b(a.y);
    r[2] = (short)f2b(a.z); r[3] = (short)f2b(a.w);
    r[4] = (short)f2b(b.x); r[5] = (short)f2b(b.y);
    r[6] = (short)f2b(b.z); r[7] = (short)f2b(b.w);
    return r;
}

// ---------------------------------------------------------------------------
// K0: xb = bf16(x)  (8 MB scratch inside Aout region, consumed by k_smean2)
// ---------------------------------------------------------------------------
__global__ __launch_bounds__(256) void k_prep(const float* __restrict__ x,
                                              u16* __restrict__ xb) {
    int id = blockIdx.x * 256 + threadIdx.x;   // 8 elements per thread
    const float4* x4 = (const float4*)x;
    float4 a = x4[2 * id];
    float4 b = x4[2 * id + 1];
    union { u16 u[8]; uint4 v; } o;
    o.u[0] = f2b(a.x); o.u[1] = f2b(a.y); o.u[2] = f2b(a.z); o.u[3] = f2b(a.w);
    o.u[4] = f2b(b.x); o.u[5] = f2b(b.y); o.u[6] = f2b(b.z); o.u[7] = f2b(b.w);
    ((uint4*)xb)[id] = o.v;
}

// ---------------------------------------------------------------------------
// K1: meanA[b,i,j] = (1/8) * sum_c A[b,c,i,j]  (unchanged, bit-exact)
// ---------------------------------------------------------------------------
__global__ __launch_bounds__(256) void k_meanA(const float* __restrict__ A,
                                               float* __restrict__ meanA) {
    int id = blockIdx.x * 256 + threadIdx.x;   // float4 index over B*N*N/4
    int b  = id >> 18;                         // N*N/4 = 262144
    int e  = id & 262143;
    const float4* A4 = (const float4*)A;
    float4 s = A4[(size_t)(b * NCA) * 262144 + e];
#pragma unroll
    for (int c = 1; c < NCA; ++c) {
        float4 v = A4[(size_t)(b * NCA + c) * 262144 + e];
        s.x += v.x; s.y += v.y; s.z += v.z; s.w += v.w;
    }
    s.x *= 0.125f; s.y *= 0.125f; s.z *= 0.125f; s.w *= 0.125f;
    ((float4*)meanA)[id] = s;
}

// ---------------------------------------------------------------------------
// K2 (fused): Smean[b,i,j] = (1/16) sum_c softmax_j(x_i . x_j)
// Block = (i-tile 16, b). Per channel: MFMA 16x1024 logits -> LDS (row stride
// 1025: banks shift by 1/row, so the 4 quarter-wave writes per store and the
// 64-lane reads are both 2-way = free) -> old-layout wave softmax (lane jg
// owns columns jg + 64u), accumulate channel mean in registers.
// MFMA layouts: A/B lane l -> row l&15, k chunk (l>>4)*8; C/D lane l, reg r
// -> row (l>>4)*4 + r, col l&15 (m89-verified).
// ---------------------------------------------------------------------------
__global__ __launch_bounds__(256, 2) void k_smean2(const u16* __restrict__ xb,
                                                   float* __restrict__ Smean) {
    __shared__ float L[16 * LSTRIDE];   // 65.6 KB
    const int t  = threadIdx.x;
    const int w  = t >> 6;              // wave id = old rg
    const int l  = t & 63;
    const int lm = l & 15;
    const int lq = l >> 4;
    const int i0 = blockIdx.x * 16;
    const int b  = blockIdx.y;
    const int jg = l;                   // old-layout lane col
    const int r4 = w * 4;               // old-layout row base
    const int rb = lq * 4;              // C/D row base for this lane

    float mean[4][16];
#pragma unroll
    for (int s = 0; s < 4; ++s)
#pragma unroll
        for (int u = 0; u < 16; ++u) mean[s][u] = 0.f;

    const int arow = i0 + lm;

    for (int c = 0; c < NCX; ++c) {
        const u16* Xc = xb + (size_t)(b * NCX + c) * NN * ND;
        // A fragments: rows i0+lm, k = 32h + lq*8 + e
        bf16x8 a0 = *(const bf16x8*)(Xc + arow * ND + lq * 8);
        bf16x8 a1 = *(const bf16x8*)(Xc + arow * ND + 32 + lq * 8);
#pragma unroll
        for (int tt = 0; tt < 16; ++tt) {
            int j0 = w * 256 + tt * 16;
            const u16* Bp = Xc + (j0 + lm) * ND;
            bf16x8 b0 = *(const bf16x8*)(Bp + lq * 8);
            bf16x8 b1 = *(const bf16x8*)(Bp + 32 + lq * 8);
            f32x4 acc = {0.f, 0.f, 0.f, 0.f};
            acc = __builtin_amdgcn_mfma_f32_16x16x32_bf16(a0, b0, acc, 0, 0, 0);
            acc = __builtin_amdgcn_mfma_f32_16x16x32_bf16(a1, b1, acc, 0, 0, 0);
            int col = j0 + lm;
            L[(rb + 0) * LSTRIDE + col] = acc[0];
            L[(rb + 1) * LSTRIDE + col] = acc[1];
            L[(rb + 2) * LSTRIDE + col] = acc[2];
            L[(rb + 3) * LSTRIDE + col] = acc[3];
        }
        __syncthreads();
        // softmax rows r4..r4+3 (old layout), accumulate into channel mean
#pragma unroll
        for (int s = 0; s < 4; ++s) {
            const float* Lp = &L[(r4 + s) * LSTRIDE];
            float v[16];
#pragma unroll
            for (int u = 0; u < 16; ++u) v[u] = Lp[jg + 64 * u];
            float m = v[0];
#pragma unroll
            for (int u = 1; u < 16; ++u) m = fmaxf(m, v[u]);
#pragma unroll
            for (int off = 32; off; off >>= 1) m = fmaxf(m, __shfl_xor(m, off, 64));
            float sum = 0.f;
#pragma unroll
            for (int u = 0; u < 16; ++u) { v[u] = __expf(v[u] - m); sum += v[u]; }
#pragma unroll
            for (int off = 32; off; off >>= 1) sum += __shfl_xor(sum, off, 64);
            float r = 1.0f / sum;
#pragma unroll
            for (int u = 0; u < 16; ++u) mean[s][u] = fmaf(v[u], r, mean[s][u]);
        }
        __syncthreads();   // before next channel overwrites L
    }
#pragma unroll
    for (int s = 0; s < 4; ++s) {
        float* Sp = Smean + ((size_t)b * NN + (i0 + r4 + s)) * NN;
#pragma unroll
        for (int u = 0; u < 16; ++u) Sp[jg + 64 * u] = mean[s][u] * 0.0625f;
    }
}

// ---------------------------------------------------------------------------
// K3: mm via MFMA (mask cvt'd to bf16 on the fly) -> LDS (stride 1025) ->
// verbatim round-0 epilogue: A_out = meanA + 0.02*sigmoid(S*mm/sqrt(10)),
// top-5 (tie -> lowest index), gather mask rows, max-reduce.
// ---------------------------------------------------------------------------
__global__ __launch_bounds__(256, 2) void k_final2(const float* __restrict__ mask,
                                                   const float* __restrict__ Smean,
                                                   const float* __restrict__ meanA,
                                                   float* __restrict__ Aout,
                                                   float* __restrict__ maskUpd) {
    __shared__ float L[16 * LSTRIDE];   // 65.6 KB
    const int t  = threadIdx.x;
    const int w  = t >> 6;
    const int l  = t & 63;
    const int lm = l & 15;
    const int lq = l >> 4;
    const int i0 = blockIdx.x * 16;
    const int c1 = blockIdx.y;
    const int b  = blockIdx.z;
    const int jg = l;
    const int r4 = w * 4;
    const int rb = lq * 4;

    const float* mbase = mask + (size_t)(b * NC1 + c1) * NN * NL;

    // A fragments from fp32 mask rows (inline RNE cvt)
    bf16x8 a0 = cvt8(mbase + (i0 + lm) * NL + lq * 8);
    bf16x8 a1 = cvt8(mbase + (i0 + lm) * NL + 32 + lq * 8);
#pragma unroll
    for (int tt = 0; tt < 16; ++tt) {
        int j0 = w * 256 + tt * 16;
        const float* Bp = mbase + (j0 + lm) * NL;
        bf16x8 b0 = cvt8(Bp + lq * 8);
        bf16x8 b1 = cvt8(Bp + 32 + lq * 8);
        f32x4 acc = {0.f, 0.f, 0.f, 0.f};
        acc = __builtin_amdgcn_mfma_f32_16x16x32_bf16(a0, b0, acc, 0, 0, 0);
        acc = __builtin_amdgcn_mfma_f32_16x16x32_bf16(a1, b1, acc, 0, 0, 0);
        int col = j0 + lm;
        L[(rb + 0) * LSTRIDE + col] = acc[0];
        L[(rb + 1) * LSTRIDE + col] = acc[1];
        L[(rb + 2) * LSTRIDE + col] = acc[2];
        L[(rb + 3) * LSTRIDE + col] = acc[3];
    }
    __syncthreads();

    // epilogue in old layout; lg holds A_out values for top-k
    float lg[4][16];
#pragma unroll
    for (int s = 0; s < 4; ++s) {
        int row = i0 + r4 + s;
        const float* Lp = &L[(r4 + s) * LSTRIDE];
        const float* Sp = Smean + ((size_t)b * NN + row) * NN;
        const float* Mp = meanA + ((size_t)b * NN + row) * NN;
        float* Ap = Aout + ((size_t)(b * NC1 + c1) * NN + row) * NN;
#pragma unroll
        for (int u = 0; u < 16; ++u) {
            int j = jg + 64 * u;
            float mmv = Lp[j];
            float Sv  = Sp[j];
            float z   = Sv * mmv * 0.31622776601683794f;  // 1/sqrt(10)
            float wv  = 1.0f / (1.0f + __expf(-z));
            float ao  = Mp[j] + 0.02f * wv;
            Ap[j] = ao;
            lg[s][u] = ao;
        }
    }

    // top-5 per row via 5-pass wave argmax (tie -> lowest index), then gather
#pragma unroll
    for (int s = 0; s < 4; ++s) {
        int row = i0 + r4 + s;
        int idxs[5];
#pragma unroll
        for (int p = 0; p < 5; ++p) {
            float bv = lg[s][0];
            int   bj = jg;
#pragma unroll
            for (int u = 1; u < 16; ++u) {
                float v = lg[s][u];
                int j = jg + 64 * u;
                if (v > bv) { bv = v; bj = j; }
            }
#pragma unroll
            for (int off = 32; off; off >>= 1) {
                float ov = __shfl_xor(bv, off, 64);
                int   oj = __shfl_xor(bj, off, 64);
                if (ov > bv || (ov == bv && oj < bj)) { bv = ov; bj = oj; }
            }
            idxs[p] = bj;
            const bool mine = (bj & 63) == jg;
            const int  cu   = bj >> 6;
#pragma unroll
            for (int u = 0; u < 16; ++u)
                lg[s][u] = (mine && u == cu) ? -INFINITY : lg[s][u];
        }
        float mx = mbase[(size_t)idxs[0] * NL + jg];
#pragma unroll
        for (int p = 1; p < 5; ++p)
            mx = fmaxf(mx, mbase[(size_t)idxs[p] * NL + jg]);
        maskUpd[((size_t)(b * NC1 + c1) * NN + row) * NL + jg] = mx;
    }
}

// ---------------------------------------------------------------------------
extern "C" void kernel_launch(void* const* d_in, const int* in_sizes, int n_in,
                              void* d_out, int out_size, void* d_ws, size_t ws_size,
                              hipStream_t stream) {
    const float* x    = (const float*)d_in[0];
    const float* A    = (const float*)d_in[1];
    const float* mask = (const float*)d_in[2];
    float* out     = (float*)d_out;
    float* Aout    = out;                                   // (B,C1,N,N)
    float* maskUpd = out + (size_t)NB * NC1 * NN * NN;      // (B,C1,N,L)
    float* meanA   = (float*)d_ws;                          // (B,N,N) 16 MB
    float* Smean   = meanA + (size_t)NB * NN * NN;          // (B,N,N) 16 MB
    u16*   xb      = (u16*)Aout;   // 8 MB bf16 scratch inside Aout region,
                                   // consumed by k_smean2 before k_final2 writes.

    hipLaunchKernelGGL(k_prep, dim3((NB * NCX * NN * ND / 8) / 256), dim3(256), 0,
                       stream, x, xb);
    hipLaunchKernelGGL(k_meanA, dim3((NB * NN * NN / 4) / 256), dim3(256), 0, stream,
                       A, meanA);
    hipLaunchKernelGGL(k_smean2, dim3(NN / 16, NB), dim3(256), 0, stream,
                       xb, Smean);
    hipLaunchKernelGGL(k_final2, dim3(NN / 16, NC1, NB), dim3(256), 0, stream,
                       mask, Smean, meanA, Aout, maskUpd);
}

// Round 3
// 693.792 us; speedup vs baseline: 1.2860x; 1.1132x over previous
//
#include <hip/hip_runtime.h>
#include <math.h>

#define NB 4
#define NCX 16
#define NC1 16
#define NCA 8
#define NN 1024
#define ND 64
#define NL 64
#define LSTRIDE 1028   // floats; %32==4 (bank shift 4/row), keeps 16B alignment

typedef __attribute__((ext_vector_type(8))) short bf16x8;
typedef __attribute__((ext_vector_type(4))) float f32x4;
typedef unsigned short u16;
typedef unsigned int u32;

// RNE float -> bf16 bits
__device__ __forceinline__ u16 f2b(float f) {
    u32 u = __float_as_uint(f);
    return (u16)((u + 0x7FFFu + ((u >> 16) & 1u)) >> 16);
}

// load 8 consecutive floats, convert to a bf16 MFMA fragment
__device__ __forceinline__ bf16x8 cvt8(const float* __restrict__ p) {
    float4 a = *(const float4*)p;
    float4 b = *(const float4*)(p + 4);
    bf16x8 r;
    r[0] = (short)f2b(a.x); r[1] = (short)f2b(a.y);
    r[2] = (short)f2b(a.z); r[3] = (short)f2b(a.w);
    r[4] = (short)f2b(b.x); r[5] = (short)f2b(b.y);
    r[6] = (short)f2b(b.z); r[7] = (short)f2b(b.w);
    return r;
}

__device__ __forceinline__ float sigm(float z) {
    return 1.0f / (1.0f + __expf(-z));
}

// ---------------------------------------------------------------------------
// K0: xb = bf16(x)  (8 MB scratch inside Aout region, consumed by k_smean3)
// ---------------------------------------------------------------------------
__global__ __launch_bounds__(256) void k_prep(const float* __restrict__ x,
                                              u16* __restrict__ xb) {
    int id = blockIdx.x * 256 + threadIdx.x;
    const float4* x4 = (const float4*)x;
    float4 a = x4[2 * id];
    float4 b = x4[2 * id + 1];
    union { u16 u[8]; uint4 v; } o;
    o.u[0] = f2b(a.x); o.u[1] = f2b(a.y); o.u[2] = f2b(a.z); o.u[3] = f2b(a.w);
    o.u[4] = f2b(b.x); o.u[5] = f2b(b.y); o.u[6] = f2b(b.z); o.u[7] = f2b(b.w);
    ((uint4*)xb)[id] = o.v;
}

// ---------------------------------------------------------------------------
// K1: meanA[b,i,j] = (1/8) * sum_c A[b,c,i,j]  (HBM roofline, unchanged)
// ---------------------------------------------------------------------------
__global__ __launch_bounds__(256) void k_meanA(const float* __restrict__ A,
                                               float* __restrict__ meanA) {
    int id = blockIdx.x * 256 + threadIdx.x;
    int b  = id >> 18;                         // N*N/4 = 262144
    int e  = id & 262143;
    const float4* A4 = (const float4*)A;
    float4 s = A4[(size_t)(b * NCA) * 262144 + e];
#pragma unroll
    for (int c = 1; c < NCA; ++c) {
        float4 v = A4[(size_t)(b * NCA + c) * 262144 + e];
        s.x += v.x; s.y += v.y; s.z += v.z; s.w += v.w;
    }
    s.x *= 0.125f; s.y *= 0.125f; s.z *= 0.125f; s.w *= 0.125f;
    ((float4*)meanA)[id] = s;
}

// ---------------------------------------------------------------------------
// K2: Smean[b,i,j] = (1/16) sum_c softmax_j(x_i . x_j)
// 1024 threads = 16 waves. Wave w computes cols [w*64, w*64+64) of the MFMA
// (4 16x16 tiles), then softmaxes ONE row (row w) per channel. Lane l owns
// columns 4l + 256u (+i), read from LDS as float4 (b128, bandwidth-floor).
// C/D layout (m89): lane -> row (l>>4)*4+reg, col l&15.
// ---------------------------------------------------------------------------
__global__ __launch_bounds__(1024, 4) void k_smean3(const u16* __restrict__ xb,
                                                    float* __restrict__ Smean) {
    __shared__ float L[16 * LSTRIDE];   // 64.25 KB
    const int t  = threadIdx.x;
    const int w  = t >> 6;              // wave 0..15
    const int l  = t & 63;
    const int lm = l & 15;
    const int lq = l >> 4;
    const int i0 = blockIdx.x * 16;
    const int b  = blockIdx.y;
    const int rb = lq * 4;              // C/D row base for this lane

    float mean[16];
#pragma unroll
    for (int u = 0; u < 16; ++u) mean[u] = 0.f;

    const int arow = i0 + lm;

    for (int c = 0; c < NCX; ++c) {
        const u16* Xc = xb + (size_t)(b * NCX + c) * NN * ND;
        bf16x8 a0 = *(const bf16x8*)(Xc + arow * ND + lq * 8);
        bf16x8 a1 = *(const bf16x8*)(Xc + arow * ND + 32 + lq * 8);
#pragma unroll
        for (int tt = 0; tt < 4; ++tt) {
            int j0 = w * 64 + tt * 16;
            const u16* Bp = Xc + (j0 + lm) * ND;
            bf16x8 b0 = *(const bf16x8*)(Bp + lq * 8);
            bf16x8 b1 = *(const bf16x8*)(Bp + 32 + lq * 8);
            f32x4 acc = {0.f, 0.f, 0.f, 0.f};
            acc = __builtin_amdgcn_mfma_f32_16x16x32_bf16(a0, b0, acc, 0, 0, 0);
            acc = __builtin_amdgcn_mfma_f32_16x16x32_bf16(a1, b1, acc, 0, 0, 0);
            int col = j0 + lm;
            L[(rb + 0) * LSTRIDE + col] = acc[0];
            L[(rb + 1) * LSTRIDE + col] = acc[1];
            L[(rb + 2) * LSTRIDE + col] = acc[2];
            L[(rb + 3) * LSTRIDE + col] = acc[3];
        }
        __syncthreads();
        // softmax of row w (this wave), cols 4l + 256u + i
        {
            const float* Lp = &L[w * LSTRIDE];
            float v[16];
#pragma unroll
            for (int u = 0; u < 4; ++u) {
                float4 q = *(const float4*)&Lp[4 * l + 256 * u];
                v[4 * u + 0] = q.x; v[4 * u + 1] = q.y;
                v[4 * u + 2] = q.z; v[4 * u + 3] = q.w;
            }
            float m = v[0];
#pragma unroll
            for (int u = 1; u < 16; ++u) m = fmaxf(m, v[u]);
#pragma unroll
            for (int off = 32; off; off >>= 1) m = fmaxf(m, __shfl_xor(m, off, 64));
            float sum = 0.f;
#pragma unroll
            for (int u = 0; u < 16; ++u) { v[u] = __expf(v[u] - m); sum += v[u]; }
#pragma unroll
            for (int off = 32; off; off >>= 1) sum += __shfl_xor(sum, off, 64);
            float r = 1.0f / sum;
#pragma unroll
            for (int u = 0; u < 16; ++u) mean[u] = fmaf(v[u], r, mean[u]);
        }
        __syncthreads();   // before next channel overwrites L
    }
    float* Sp = Smean + ((size_t)b * NN + (i0 + w)) * NN;
#pragma unroll
    for (int u = 0; u < 4; ++u) {
        float4 o;
        o.x = mean[4 * u + 0] * 0.0625f;
        o.y = mean[4 * u + 1] * 0.0625f;
        o.z = mean[4 * u + 2] * 0.0625f;
        o.w = mean[4 * u + 3] * 0.0625f;
        *(float4*)(Sp + 4 * l + 256 * u) = o;
    }
}

// ---------------------------------------------------------------------------
// K3: mm via MFMA (mask cvt'd to bf16 on the fly) -> LDS -> per-wave-row
// epilogue (float4 global ops): A_out = meanA + 0.02*sigmoid(S*mm/sqrt(10)),
// top-5 (tie -> lowest index), gather mask rows, max-reduce.
// 1024 threads = 16 waves; wave w owns row i0+w. Lane l owns cols 4l+256u+i.
// ---------------------------------------------------------------------------
__global__ __launch_bounds__(1024, 4) void k_final3(const float* __restrict__ mask,
                                                    const float* __restrict__ Smean,
                                                    const float* __restrict__ meanA,
                                                    float* __restrict__ Aout,
                                                    float* __restrict__ maskUpd) {
    __shared__ float L[16 * LSTRIDE];   // 64.25 KB
    const int t  = threadIdx.x;
    const int w  = t >> 6;
    const int l  = t & 63;
    const int lm = l & 15;
    const int lq = l >> 4;
    const int i0 = blockIdx.x * 16;
    const int c1 = blockIdx.y;
    const int b  = blockIdx.z;
    const int rb = lq * 4;

    const float* mbase = mask + (size_t)(b * NC1 + c1) * NN * NL;

    bf16x8 a0 = cvt8(mbase + (i0 + lm) * NL + lq * 8);
    bf16x8 a1 = cvt8(mbase + (i0 + lm) * NL + 32 + lq * 8);
#pragma unroll
    for (int tt = 0; tt < 4; ++tt) {
        int j0 = w * 64 + tt * 16;
        const float* Bp = mbase + (j0 + lm) * NL;
        bf16x8 b0 = cvt8(Bp + lq * 8);
        bf16x8 b1 = cvt8(Bp + 32 + lq * 8);
        f32x4 acc = {0.f, 0.f, 0.f, 0.f};
        acc = __builtin_amdgcn_mfma_f32_16x16x32_bf16(a0, b0, acc, 0, 0, 0);
        acc = __builtin_amdgcn_mfma_f32_16x16x32_bf16(a1, b1, acc, 0, 0, 0);
        int col = j0 + lm;
        L[(rb + 0) * LSTRIDE + col] = acc[0];
        L[(rb + 1) * LSTRIDE + col] = acc[1];
        L[(rb + 2) * LSTRIDE + col] = acc[2];
        L[(rb + 3) * LSTRIDE + col] = acc[3];
    }
    __syncthreads();

    const int row = i0 + w;
    const float* Lp = &L[w * LSTRIDE];
    const float* Sp = Smean + ((size_t)b * NN + row) * NN;
    const float* Mp = meanA + ((size_t)b * NN + row) * NN;
    float* Ap = Aout + ((size_t)(b * NC1 + c1) * NN + row) * NN;

    float lg[16];
#pragma unroll
    for (int u = 0; u < 4; ++u) {
        int j = 4 * l + 256 * u;
        float4 mm4 = *(const float4*)&Lp[j];
        float4 S4  = *(const float4*)(Sp + j);
        float4 M4  = *(const float4*)(Mp + j);
        float4 o;
        o.x = M4.x + 0.02f * sigm(S4.x * mm4.x * 0.31622776601683794f);
        o.y = M4.y + 0.02f * sigm(S4.y * mm4.y * 0.31622776601683794f);
        o.z = M4.z + 0.02f * sigm(S4.z * mm4.z * 0.31622776601683794f);
        o.w = M4.w + 0.02f * sigm(S4.w * mm4.w * 0.31622776601683794f);
        *(float4*)(Ap + j) = o;
        lg[4 * u + 0] = o.x; lg[4 * u + 1] = o.y;
        lg[4 * u + 2] = o.z; lg[4 * u + 3] = o.w;
    }

    // top-5 for row (this wave). Lane l's element k maps to
    // j = 4l + 256*(k>>2) + (k&3); ascending in k -> strict > keeps lowest j.
    int idxs[5];
#pragma unroll
    for (int p = 0; p < 5; ++p) {
        float bv = lg[0];
        int   bj = 4 * l;
#pragma unroll
        for (int k = 1; k < 16; ++k) {
            int j = 4 * l + 256 * (k >> 2) + (k & 3);
            if (lg[k] > bv) { bv = lg[k]; bj = j; }
        }
#pragma unroll
        for (int off = 32; off; off >>= 1) {
            float ov = __shfl_xor(bv, off, 64);
            int   oj = __shfl_xor(bj, off, 64);
            if (ov > bv || (ov == bv && oj < bj)) { bv = ov; bj = oj; }
        }
        idxs[p] = bj;
        const bool mine = ((bj & 255) >> 2) == l;
        const int  ck   = (bj >> 8) * 4 + (bj & 3);
#pragma unroll
        for (int k = 0; k < 16; ++k)
            lg[k] = (mine && k == ck) ? -INFINITY : lg[k];
    }
    float mx = mbase[(size_t)idxs[0] * NL + l];
#pragma unroll
    for (int p = 1; p < 5; ++p)
        mx = fmaxf(mx, mbase[(size_t)idxs[p] * NL + l]);
    maskUpd[((size_t)(b * NC1 + c1) * NN + row) * NL + l] = mx;
}

// ---------------------------------------------------------------------------
extern "C" void kernel_launch(void* const* d_in, const int* in_sizes, int n_in,
                              void* d_out, int out_size, void* d_ws, size_t ws_size,
                              hipStream_t stream) {
    const float* x    = (const float*)d_in[0];
    const float* A    = (const float*)d_in[1];
    const float* mask = (const float*)d_in[2];
    float* out     = (float*)d_out;
    float* Aout    = out;                                   // (B,C1,N,N)
    float* maskUpd = out + (size_t)NB * NC1 * NN * NN;      // (B,C1,N,L)
    float* meanA   = (float*)d_ws;                          // (B,N,N) 16 MB
    float* Smean   = meanA + (size_t)NB * NN * NN;          // (B,N,N) 16 MB
    u16*   xb      = (u16*)Aout;   // 8 MB bf16 scratch inside Aout region,
                                   // consumed by k_smean3 before k_final3 writes.

    hipLaunchKernelGGL(k_prep, dim3((NB * NCX * NN * ND / 8) / 256), dim3(256), 0,
                       stream, x, xb);
    hipLaunchKernelGGL(k_meanA, dim3((NB * NN * NN / 4) / 256), dim3(256), 0, stream,
                       A, meanA);
    hipLaunchKernelGGL(k_smean3, dim3(NN / 16, NB), dim3(1024), 0, stream,
                       xb, Smean);
    hipLaunchKernelGGL(k_final3, dim3(NN / 16, NC1, NB), dim3(1024), 0, stream,
                       mask, Smean, meanA, Aout, maskUpd);
}

// Round 4
// 593.380 us; speedup vs baseline: 1.5036x; 1.1692x over previous
//
#include <hip/hip_runtime.h>
#include <math.h>

#define NB 4
#define NCX 16
#define NC1 16
#define NCA 8
#define NN 1024
#define ND 64
#define NL 64
#define LSTRIDE 1028   // floats; %32==4 (bank shift 4/row), keeps 16B alignment
#define NCG 4          // channel groups for k_smean partials

typedef __attribute__((ext_vector_type(8))) short bf16x8;
typedef __attribute__((ext_vector_type(4))) float f32x4;
typedef unsigned short u16;
typedef unsigned int u32;

// RNE float -> bf16 bits
__device__ __forceinline__ u16 f2b(float f) {
    u32 u = __float_as_uint(f);
    return (u16)((u + 0x7FFFu + ((u >> 16) & 1u)) >> 16);
}

// load 8 consecutive floats, convert to a bf16 MFMA fragment
__device__ __forceinline__ bf16x8 cvt8(const float* __restrict__ p) {
    float4 a = *(const float4*)p;
    float4 b = *(const float4*)(p + 4);
    bf16x8 r;
    r[0] = (short)f2b(a.x); r[1] = (short)f2b(a.y);
    r[2] = (short)f2b(a.z); r[3] = (short)f2b(a.w);
    r[4] = (short)f2b(b.x); r[5] = (short)f2b(b.y);
    r[6] = (short)f2b(b.z); r[7] = (short)f2b(b.w);
    return r;
}

__device__ __forceinline__ float sigm(float z) {
    return 1.0f / (1.0f + __expf(-z));
}

// ---------------------------------------------------------------------------
// K0: generic fp32 -> bf16 (8 elems/thread). Used for x->xb and mask->maskb.
// ---------------------------------------------------------------------------
__global__ __launch_bounds__(256) void k_cvt(const float* __restrict__ src,
                                             u16* __restrict__ dst) {
    int id = blockIdx.x * 256 + threadIdx.x;
    const float4* x4 = (const float4*)src;
    float4 a = x4[2 * id];
    float4 b = x4[2 * id + 1];
    union { u16 u[8]; uint4 v; } o;
    o.u[0] = f2b(a.x); o.u[1] = f2b(a.y); o.u[2] = f2b(a.z); o.u[3] = f2b(a.w);
    o.u[4] = f2b(b.x); o.u[5] = f2b(b.y); o.u[6] = f2b(b.z); o.u[7] = f2b(b.w);
    ((uint4*)dst)[id] = o.v;
}

// ---------------------------------------------------------------------------
// K1: meanA[b,i,j] = (1/8) * sum_c A[b,c,i,j]
// ---------------------------------------------------------------------------
__global__ __launch_bounds__(256) void k_meanA(const float* __restrict__ A,
                                               float* __restrict__ meanA) {
    int id = blockIdx.x * 256 + threadIdx.x;
    int b  = id >> 18;                         // N*N/4 = 262144
    int e  = id & 262143;
    const float4* A4 = (const float4*)A;
    float4 s = A4[(size_t)(b * NCA) * 262144 + e];
#pragma unroll
    for (int c = 1; c < NCA; ++c) {
        float4 v = A4[(size_t)(b * NCA + c) * 262144 + e];
        s.x += v.x; s.y += v.y; s.z += v.z; s.w += v.w;
    }
    s.x *= 0.125f; s.y *= 0.125f; s.z *= 0.125f; s.w *= 0.125f;
    ((float4*)meanA)[id] = s;
}

// ---------------------------------------------------------------------------
// K2: partial softmax-sums. Block (i-tile, b, cg) handles 4 channels and
// writes Spart[cg][b][i][j] = sum_{c in group} softmax_j(x_i . x_j).
// 1024 blocks -> 2 resident/CU (LDS 64.25 KB); stage/softmax phases of the
// two blocks interleave, hiding each other's latency.
// 16 waves; wave w computes cols [w*64,w*64+64) (4 MFMA tiles) then
// softmaxes row w. Lane l owns cols 4l + 256u (+i), float4 LDS reads.
// ---------------------------------------------------------------------------
__global__ __launch_bounds__(1024, 8) void k_smean4(const u16* __restrict__ xb,
                                                    float* __restrict__ Spart) {
    __shared__ float L[16 * LSTRIDE];   // 64.25 KB
    const int t  = threadIdx.x;
    const int w  = t >> 6;              // wave 0..15
    const int l  = t & 63;
    const int lm = l & 15;
    const int lq = l >> 4;
    const int i0 = blockIdx.x * 16;
    const int b  = blockIdx.y;
    const int cg = blockIdx.z;
    const int rb = lq * 4;              // C/D row base for this lane

    float mean[16];
#pragma unroll
    for (int u = 0; u < 16; ++u) mean[u] = 0.f;

    const int arow = i0 + lm;

    for (int c = cg * 4; c < cg * 4 + 4; ++c) {
        const u16* Xc = xb + (size_t)(b * NCX + c) * NN * ND;
        bf16x8 a0 = *(const bf16x8*)(Xc + arow * ND + lq * 8);
        bf16x8 a1 = *(const bf16x8*)(Xc + arow * ND + 32 + lq * 8);
#pragma unroll
        for (int tt = 0; tt < 4; ++tt) {
            int j0 = w * 64 + tt * 16;
            const u16* Bp = Xc + (j0 + lm) * ND;
            bf16x8 b0 = *(const bf16x8*)(Bp + lq * 8);
            bf16x8 b1 = *(const bf16x8*)(Bp + 32 + lq * 8);
            f32x4 acc = {0.f, 0.f, 0.f, 0.f};
            acc = __builtin_amdgcn_mfma_f32_16x16x32_bf16(a0, b0, acc, 0, 0, 0);
            acc = __builtin_amdgcn_mfma_f32_16x16x32_bf16(a1, b1, acc, 0, 0, 0);
            int col = j0 + lm;
            L[(rb + 0) * LSTRIDE + col] = acc[0];
            L[(rb + 1) * LSTRIDE + col] = acc[1];
            L[(rb + 2) * LSTRIDE + col] = acc[2];
            L[(rb + 3) * LSTRIDE + col] = acc[3];
        }
        __syncthreads();
        {
            const float* Lp = &L[w * LSTRIDE];
            float v[16];
#pragma unroll
            for (int u = 0; u < 4; ++u) {
                float4 q = *(const float4*)&Lp[4 * l + 256 * u];
                v[4 * u + 0] = q.x; v[4 * u + 1] = q.y;
                v[4 * u + 2] = q.z; v[4 * u + 3] = q.w;
            }
            float m = v[0];
#pragma unroll
            for (int u = 1; u < 16; ++u) m = fmaxf(m, v[u]);
#pragma unroll
            for (int off = 32; off; off >>= 1) m = fmaxf(m, __shfl_xor(m, off, 64));
            float sum = 0.f;
#pragma unroll
            for (int u = 0; u < 16; ++u) { v[u] = __expf(v[u] - m); sum += v[u]; }
#pragma unroll
            for (int off = 32; off; off >>= 1) sum += __shfl_xor(sum, off, 64);
            float r = 1.0f / sum;
#pragma unroll
            for (int u = 0; u < 16; ++u) mean[u] = fmaf(v[u], r, mean[u]);
        }
        __syncthreads();   // before next channel overwrites L
    }
    float* Sp = Spart + (((size_t)(cg * NB + b)) * NN + (i0 + w)) * NN;
#pragma unroll
    for (int u = 0; u < 4; ++u) {
        float4 o;
        o.x = mean[4 * u + 0]; o.y = mean[4 * u + 1];
        o.z = mean[4 * u + 2]; o.w = mean[4 * u + 3];
        *(float4*)(Sp + 4 * l + 256 * u) = o;
    }
}

// ---------------------------------------------------------------------------
// K2b: Smean = (1/16) * (P0+P1+P2+P3)
// ---------------------------------------------------------------------------
__global__ __launch_bounds__(256) void k_sred(const float* __restrict__ Spart,
                                              float* __restrict__ Smean) {
    int id = blockIdx.x * 256 + threadIdx.x;   // float4 index over B*N*N/4
    int b  = id >> 18;
    int e  = id & 262143;
    const float4* P4 = (const float4*)Spart;
    float4 s = P4[(size_t)b * 262144 + e];
#pragma unroll
    for (int g = 1; g < NCG; ++g) {
        float4 v = P4[(size_t)(g * NB + b) * 262144 + e];
        s.x += v.x; s.y += v.y; s.z += v.z; s.w += v.w;
    }
    s.x *= 0.0625f; s.y *= 0.0625f; s.z *= 0.0625f; s.w *= 0.0625f;
    ((float4*)Smean)[id] = s;
}

// ---------------------------------------------------------------------------
// K3: mm via MFMA (bf16 fragments from maskb if available, else inline cvt)
// -> LDS -> per-wave-row epilogue: A_out = meanA + 0.02*sigmoid(S*mm/sqrt(10)),
// top-5 (tie -> lowest index), gather fp32 mask rows, max-reduce.
// S row preloaded into regs before the barrier (hides L2 latency under MFMA).
// ---------------------------------------------------------------------------
template <bool MB>
__global__ __launch_bounds__(1024, 8) void k_final4(const float* __restrict__ mask,
                                                    const u16* __restrict__ maskb,
                                                    const float* __restrict__ Smean,
                                                    const float* __restrict__ meanA,
                                                    float* __restrict__ Aout,
                                                    float* __restrict__ maskUpd) {
    __shared__ float L[16 * LSTRIDE];   // 64.25 KB
    const int t  = threadIdx.x;
    const int w  = t >> 6;
    const int l  = t & 63;
    const int lm = l & 15;
    const int lq = l >> 4;
    const int i0 = blockIdx.x * 16;
    const int c1 = blockIdx.y;
    const int b  = blockIdx.z;
    const int rb = lq * 4;
    const int row = i0 + w;

    const float* mbase = mask + (size_t)(b * NC1 + c1) * NN * NL;
    const u16*   mbb   = maskb + (size_t)(b * NC1 + c1) * NN * NL;

    bf16x8 a0, a1;
    if (MB) {
        a0 = *(const bf16x8*)(mbb + (i0 + lm) * NL + lq * 8);
        a1 = *(const bf16x8*)(mbb + (i0 + lm) * NL + 32 + lq * 8);
    } else {
        a0 = cvt8(mbase + (i0 + lm) * NL + lq * 8);
        a1 = cvt8(mbase + (i0 + lm) * NL + 32 + lq * 8);
    }
#pragma unroll
    for (int tt = 0; tt < 4; ++tt) {
        int j0 = w * 64 + tt * 16;
        bf16x8 b0, b1;
        if (MB) {
            const u16* Bp = mbb + (j0 + lm) * NL;
            b0 = *(const bf16x8*)(Bp + lq * 8);
            b1 = *(const bf16x8*)(Bp + 32 + lq * 8);
        } else {
            const float* Bp = mbase + (j0 + lm) * NL;
            b0 = cvt8(Bp + lq * 8);
            b1 = cvt8(Bp + 32 + lq * 8);
        }
        f32x4 acc = {0.f, 0.f, 0.f, 0.f};
        acc = __builtin_amdgcn_mfma_f32_16x16x32_bf16(a0, b0, acc, 0, 0, 0);
        acc = __builtin_amdgcn_mfma_f32_16x16x32_bf16(a1, b1, acc, 0, 0, 0);
        int col = j0 + lm;
        L[(rb + 0) * LSTRIDE + col] = acc[0];
        L[(rb + 1) * LSTRIDE + col] = acc[1];
        L[(rb + 2) * LSTRIDE + col] = acc[2];
        L[(rb + 3) * LSTRIDE + col] = acc[3];
    }

    // preload this wave's Smean row (independent of LDS; hides under barrier)
    const float* Sp = Smean + ((size_t)b * NN + row) * NN;
    float4 S4r[4];
#pragma unroll
    for (int u = 0; u < 4; ++u) S4r[u] = *(const float4*)(Sp + 4 * l + 256 * u);

    __syncthreads();

    const float* Lp = &L[w * LSTRIDE];
    const float* Mp = meanA + ((size_t)b * NN + row) * NN;
    float* Ap = Aout + ((size_t)(b * NC1 + c1) * NN + row) * NN;

    float lg[16];
#pragma unroll
    for (int u = 0; u < 4; ++u) {
        int j = 4 * l + 256 * u;
        float4 mm4 = *(const float4*)&Lp[j];
        float4 S4  = S4r[u];
        float4 M4  = *(const float4*)(Mp + j);
        float4 o;
        o.x = M4.x + 0.02f * sigm(S4.x * mm4.x * 0.31622776601683794f);
        o.y = M4.y + 0.02f * sigm(S4.y * mm4.y * 0.31622776601683794f);
        o.z = M4.z + 0.02f * sigm(S4.z * mm4.z * 0.31622776601683794f);
        o.w = M4.w + 0.02f * sigm(S4.w * mm4.w * 0.31622776601683794f);
        *(float4*)(Ap + j) = o;
        lg[4 * u + 0] = o.x; lg[4 * u + 1] = o.y;
        lg[4 * u + 2] = o.z; lg[4 * u + 3] = o.w;
    }

    // top-5 (lane l's element k -> col j = 4l + 256*(k>>2) + (k&3);
    // ascending in k so strict > keeps the lowest index locally)
    int idxs[5];
#pragma unroll
    for (int p = 0; p < 5; ++p) {
        float bv = lg[0];
        int   bj = 4 * l;
#pragma unroll
        for (int k = 1; k < 16; ++k) {
            int j = 4 * l + 256 * (k >> 2) + (k & 3);
            if (lg[k] > bv) { bv = lg[k]; bj = j; }
        }
#pragma unroll
        for (int off = 32; off; off >>= 1) {
            float ov = __shfl_xor(bv, off, 64);
            int   oj = __shfl_xor(bj, off, 64);
            if (ov > bv || (ov == bv && oj < bj)) { bv = ov; bj = oj; }
        }
        idxs[p] = bj;
        const bool mine = ((bj & 255) >> 2) == l;
        const int  ck   = (bj >> 8) * 4 + (bj & 3);
#pragma unroll
        for (int k = 0; k < 16; ++k)
            lg[k] = (mine && k == ck) ? -INFINITY : lg[k];
    }
    float mx = mbase[(size_t)idxs[0] * NL + l];
#pragma unroll
    for (int p = 1; p < 5; ++p)
        mx = fmaxf(mx, mbase[(size_t)idxs[p] * NL + l]);
    maskUpd[((size_t)(b * NC1 + c1) * NN + row) * NL + l] = mx;
}

// ---------------------------------------------------------------------------
extern "C" void kernel_launch(void* const* d_in, const int* in_sizes, int n_in,
                              void* d_out, int out_size, void* d_ws, size_t ws_size,
                              hipStream_t stream) {
    const float* x    = (const float*)d_in[0];
    const float* A    = (const float*)d_in[1];
    const float* mask = (const float*)d_in[2];
    float* out     = (float*)d_out;
    float* Aout    = out;                                   // (B,C1,N,N)
    float* maskUpd = out + (size_t)NB * NC1 * NN * NN;      // (B,C1,N,L)
    float* meanA   = (float*)d_ws;                          // (B,N,N)  16.8 MB
    float* Smean   = meanA + (size_t)NB * NN * NN;          // (B,N,N)  16.8 MB
    u16*   maskb   = (u16*)(Smean + (size_t)NB * NN * NN);  // 8.4 MB (guarded)
    const bool useMB = ws_size >= (size_t)(2 * NB * NN * NN * 4 + NB * NC1 * NN * NL * 2);

    // scratch inside the Aout region (consumed before k_final4 writes it):
    u16*   xb    = (u16*)Aout;                          // 8.4 MB bf16 x
    float* Spart = Aout + (size_t)16777216;             // 4 partials x 16.8 MB

    hipLaunchKernelGGL(k_cvt, dim3((NB * NCX * NN * ND / 8) / 256), dim3(256), 0,
                       stream, x, xb);
    if (useMB)
        hipLaunchKernelGGL(k_cvt, dim3((NB * NC1 * NN * NL / 8) / 256), dim3(256), 0,
                           stream, mask, (u16*)maskb);
    hipLaunchKernelGGL(k_meanA, dim3((NB * NN * NN / 4) / 256), dim3(256), 0, stream,
                       A, meanA);
    hipLaunchKernelGGL(k_smean4, dim3(NN / 16, NB, NCG), dim3(1024), 0, stream,
                       xb, Spart);
    hipLaunchKernelGGL(k_sred, dim3((NB * NN * NN / 4) / 256), dim3(256), 0, stream,
                       Spart, Smean);
    if (useMB)
        hipLaunchKernelGGL(k_final4<true>, dim3(NN / 16, NC1, NB), dim3(1024), 0,
                           stream, mask, maskb, Smean, meanA, Aout, maskUpd);
    else
        hipLaunchKernelGGL(k_final4<false>, dim3(NN / 16, NC1, NB), dim3(1024), 0,
                           stream, mask, maskb, Smean, meanA, Aout, maskUpd);
}